// Round 1
// baseline (835.580 us; speedup 1.0000x reference)
//
#include <hip/hip_runtime.h>
#include <hip/hip_bf16.h>
#include <math.h>

#define EMB 1024
#define DIM_FF 4096
#define HEADS 16
#define HD 64
#define TSEQ 2048
#define BATCH 4
#define MROWS (BATCH*TSEQ)
#define LN_EPS 1e-5f

typedef __attribute__((ext_vector_type(8))) short short8;
typedef __attribute__((ext_vector_type(4))) float f32x4;

#define MFMA16(a,b,c) __builtin_amdgcn_mfma_f32_16x16x32_bf16((a),(b),(c),0,0,0)

__device__ __forceinline__ int swzA(int r){ return ((r>>1)&3)<<3; }

__device__ __forceinline__ unsigned short bf16bits(float f){
    __hip_bfloat16 h = __float2bfloat16(f);
    unsigned short u;
    __builtin_memcpy(&u, &h, 2);
    return u;
}

// ---------------- convert fp32 -> bf16 (row-major) ----------------
__global__ __launch_bounds__(256)
void cvt_bf16(const float* __restrict__ in, __hip_bfloat16* __restrict__ out, int n4){
    int i = blockIdx.x*256 + threadIdx.x;
    if (i >= n4) return;
    f32x4 v = reinterpret_cast<const f32x4*>(in)[i];
    union { unsigned short us[4]; uint2 u2; } o;
    #pragma unroll
    for (int j=0;j<4;++j) o.us[j] = bf16bits(v[j]);
    *reinterpret_cast<uint2*>(reinterpret_cast<unsigned short*>(out) + (size_t)i*4) = o.u2;
}

// ---------------- transpose + convert: in (R x C) fp32 -> out (C x R) bf16 ----------------
__global__ __launch_bounds__(256)
void transpose_cvt(const float* __restrict__ in, __hip_bfloat16* __restrict__ out, int R, int C){
    __shared__ __hip_bfloat16 tile[32][33];
    int bx = blockIdx.x*32;  // col base
    int by = blockIdx.y*32;  // row base
    int x = bx + threadIdx.x;
    #pragma unroll
    for (int i = threadIdx.y; i < 32; i += 8){
        tile[i][threadIdx.x] = __float2bfloat16(in[(size_t)(by+i)*C + x]);
    }
    __syncthreads();
    int xo = by + threadIdx.x; // new col = old row
    #pragma unroll
    for (int i = threadIdx.y; i < 32; i += 8){
        out[(size_t)(bx+i)*R + xo] = tile[threadIdx.x][i];
    }
}

// ---------------- GEMM: C[M,N] = A[M,K](bf16) * Bt[N,K](bf16)^T ----------------
// EPI: 0 = QKV scatter, 1 = f32 out, 2 = +bias,relu -> bf16, 3 = +bias -> f32
template<int EPI>
__global__ __launch_bounds__(256, 2)
void gemm_bt(const __hip_bfloat16* __restrict__ A,
             const __hip_bfloat16* __restrict__ Bt,
             int M, int N, int K,
             float* __restrict__ Cf,
             __hip_bfloat16* __restrict__ Cb,
             const float* __restrict__ bias,
             __hip_bfloat16* __restrict__ qo,
             __hip_bfloat16* __restrict__ ko,
             __hip_bfloat16* __restrict__ vto)
{
    __shared__ __align__(16) __hip_bfloat16 As[128*32];
    __shared__ __align__(16) __hip_bfloat16 Bs[128*32];
    const int tid = threadIdx.x;
    const int lane = tid & 63;
    const int wid = tid >> 6;
    const int wm = wid >> 1, wn = wid & 1;
    const int row0 = blockIdx.x * 128;
    const int col0 = blockIdx.y * 128;
    const int rA = lane & 15, kg = lane >> 4;

    f32x4 acc[4][4] = {};

    const int sr = tid >> 2;          // 0..63
    const int sc = (tid & 3) << 3;    // 0,8,16,24

    for (int kt = 0; kt < K; kt += 32) {
        __syncthreads();
        #pragma unroll
        for (int rr = sr; rr < 128; rr += 64) {
            uint4 av = *reinterpret_cast<const uint4*>(A + (size_t)(row0+rr)*K + kt + sc);
            *reinterpret_cast<uint4*>(&As[rr*32 + (sc ^ swzA(rr))]) = av;
            uint4 bv = *reinterpret_cast<const uint4*>(Bt + (size_t)(col0+rr)*K + kt + sc);
            *reinterpret_cast<uint4*>(&Bs[rr*32 + (sc ^ swzA(rr))]) = bv;
        }
        __syncthreads();
        short8 af[4], bfr[4];
        #pragma unroll
        for (int mi = 0; mi < 4; ++mi) {
            int r = wm*64 + mi*16 + rA;
            af[mi] = *reinterpret_cast<const short8*>(&As[r*32 + ((kg<<3) ^ swzA(r))]);
        }
        #pragma unroll
        for (int ni = 0; ni < 4; ++ni) {
            int r = wn*64 + ni*16 + rA;
            bfr[ni] = *reinterpret_cast<const short8*>(&Bs[r*32 + ((kg<<3) ^ swzA(r))]);
        }
        #pragma unroll
        for (int mi = 0; mi < 4; ++mi)
            #pragma unroll
            for (int ni = 0; ni < 4; ++ni)
                acc[mi][ni] = MFMA16(af[mi], bfr[ni], acc[mi][ni]);
    }

    #pragma unroll
    for (int mi=0; mi<4; ++mi) {
        #pragma unroll
        for (int ni=0; ni<4; ++ni) {
            #pragma unroll
            for (int j=0;j<4;++j){
                float v = acc[mi][ni][j];
                int grow = row0 + wm*64 + mi*16 + (kg<<2) + j;
                int gcol = col0 + wn*64 + ni*16 + rA;
                if constexpr (EPI==0) {
                    int b = grow >> 11, t = grow & 2047;
                    int which = gcol >> 10, hdx = gcol & 1023;
                    int h = hdx >> 6, d = hdx & 63;
                    int bh = b*HEADS + h;
                    __hip_bfloat16 bv = __float2bfloat16(v);
                    if (which==0)      qo[((size_t)bh*TSEQ + t)*HD + d] = bv;
                    else if (which==1) ko[((size_t)bh*TSEQ + t)*HD + d] = bv;
                    else               vto[((size_t)bh*HD + d)*TSEQ + t] = bv;
                } else if constexpr (EPI==1) {
                    Cf[(size_t)grow*N + gcol] = v;
                } else if constexpr (EPI==2) {
                    v += bias[gcol]; v = v > 0.0f ? v : 0.0f;
                    Cb[(size_t)grow*N + gcol] = __float2bfloat16(v);
                } else {
                    Cf[(size_t)grow*N + gcol] = v + bias[gcol];
                }
            }
        }
    }
}

// ---------------- flash attention ----------------
// q,k: [BH][T][64] bf16 ; vt: [BH][64][T] bf16 ; merged: [B*T][1024] bf16
__global__ __launch_bounds__(256, 2)
void attn_fwd(const __hip_bfloat16* __restrict__ q,
              const __hip_bfloat16* __restrict__ k,
              const __hip_bfloat16* __restrict__ vt,
              __hip_bfloat16* __restrict__ merged)
{
    const int bh = blockIdx.y;
    const int wid = threadIdx.x >> 6, lane = threadIdx.x & 63;
    const int rA = lane & 15, kg = lane >> 4;
    const int qrow0 = blockIdx.x*64 + wid*16;
    const __hip_bfloat16* Qh = q  + (size_t)bh*TSEQ*HD;
    const __hip_bfloat16* Kh = k  + (size_t)bh*TSEQ*HD;
    const __hip_bfloat16* Vh = vt + (size_t)bh*HD*TSEQ;
    __shared__ __align__(16) __hip_bfloat16 plds[4][16][40];

    short8 aQ0 = *reinterpret_cast<const short8*>(Qh + (size_t)(qrow0+rA)*HD + (kg<<3));
    short8 aQ1 = *reinterpret_cast<const short8*>(Qh + (size_t)(qrow0+rA)*HD + 32 + (kg<<3));

    f32x4 O[4] = {};
    float m[4] = {-1e30f,-1e30f,-1e30f,-1e30f};
    float l[4] = {0.f,0.f,0.f,0.f};

    for (int kt=0; kt<TSEQ; kt+=32) {
        f32x4 s0 = {}, s1 = {};
        {
            const __hip_bfloat16* Kb = Kh + (size_t)(kt+rA)*HD + (kg<<3);
            short8 b00 = *reinterpret_cast<const short8*>(Kb);
            short8 b01 = *reinterpret_cast<const short8*>(Kb + 32);
            s0 = MFMA16(aQ0, b00, s0); s0 = MFMA16(aQ1, b01, s0);
            short8 b10 = *reinterpret_cast<const short8*>(Kb + 16*HD);
            short8 b11 = *reinterpret_cast<const short8*>(Kb + 16*HD + 32);
            s1 = MFMA16(aQ0, b10, s1); s1 = MFMA16(aQ1, b11, s1);
        }
        float alpha[4];
        #pragma unroll
        for (int j=0;j<4;++j){
            float sv0 = s0[j]*0.125f, sv1 = s1[j]*0.125f;
            float mx = fmaxf(sv0, sv1);
            #pragma unroll
            for (int off=1; off<16; off<<=1) mx = fmaxf(mx, __shfl_xor(mx, off));
            float mn = fmaxf(m[j], mx);
            float al = __expf(m[j]-mn);
            float p0 = __expf(sv0-mn), p1 = __expf(sv1-mn);
            float rs = p0+p1;
            #pragma unroll
            for (int off=1; off<16; off<<=1) rs += __shfl_xor(rs, off);
            m[j]=mn; l[j]=l[j]*al+rs; alpha[j]=al;
            s0[j]=p0; s1[j]=p1;
        }
        #pragma unroll
        for (int dt=0; dt<4; ++dt)
            #pragma unroll
            for (int j=0;j<4;++j) O[dt][j]*=alpha[j];

        __syncthreads();
        #pragma unroll
        for (int j=0;j<4;++j){
            plds[wid][(kg<<2)+j][rA]    = __float2bfloat16(s0[j]);
            plds[wid][(kg<<2)+j][16+rA] = __float2bfloat16(s1[j]);
        }
        __syncthreads();
        short8 aP = *reinterpret_cast<const short8*>(&plds[wid][rA][kg<<3]);
        #pragma unroll
        for (int dt=0; dt<4; ++dt){
            short8 bV = *reinterpret_cast<const short8*>(Vh + (size_t)(dt*16+rA)*TSEQ + kt + (kg<<3));
            O[dt] = MFMA16(aP, bV, O[dt]);
        }
    }
    const int b = bh >> 4, h = bh & 15;
    #pragma unroll
    for (int dt=0; dt<4; ++dt){
        #pragma unroll
        for (int j=0;j<4;++j){
            int t = qrow0 + (kg<<2) + j;
            int col = h*HD + dt*16 + rA;
            merged[((size_t)(b*TSEQ + t))*EMB + col] = __float2bfloat16(O[dt][j]/l[j]);
        }
    }
}

// ---------------- residual + layer norm ----------------
__global__ __launch_bounds__(256)
void ln_res(const float* __restrict__ a, const float* __restrict__ res,
            const float* __restrict__ gain, const float* __restrict__ bias,
            float* __restrict__ outf, __hip_bfloat16* __restrict__ outb)
{
    const int row = blockIdx.x;
    const int tid = threadIdx.x;
    const int lane = tid & 63, wid = tid >> 6;
    const size_t base = (size_t)row * EMB;
    f32x4 va = *reinterpret_cast<const f32x4*>(a + base + tid*4);
    f32x4 vr = *reinterpret_cast<const f32x4*>(res + base + tid*4);
    f32x4 v = va + vr;
    float s = v[0]+v[1]+v[2]+v[3];
    #pragma unroll
    for (int off=1; off<64; off<<=1) s += __shfl_xor(s, off);
    __shared__ float red1[4], red2[4];
    if (lane==0) red1[wid] = s;
    __syncthreads();
    float mean = (red1[0]+red1[1]+red1[2]+red1[3]) * (1.0f/EMB);
    f32x4 d;
    #pragma unroll
    for (int j=0;j<4;++j) d[j] = v[j] - mean;
    float qs = d[0]*d[0]+d[1]*d[1]+d[2]*d[2]+d[3]*d[3];
    #pragma unroll
    for (int off=1; off<64; off<<=1) qs += __shfl_xor(qs, off);
    if (lane==0) red2[wid] = qs;
    __syncthreads();
    float var = (red2[0]+red2[1]+red2[2]+red2[3]) * (1.0f/EMB);
    float r = 1.0f/(sqrtf(var)+LN_EPS);
    f32x4 g = *reinterpret_cast<const f32x4*>(gain + tid*4);
    f32x4 bb = *reinterpret_cast<const f32x4*>(bias + tid*4);
    f32x4 o;
    #pragma unroll
    for (int j=0;j<4;++j) o[j] = g[j]*(d[j]*r) + bb[j];
    *reinterpret_cast<f32x4*>(outf + base + tid*4) = o;
    if (outb) {
        union { unsigned short us[4]; uint2 u2; } ob;
        #pragma unroll
        for (int j=0;j<4;++j) ob.us[j] = bf16bits(o[j]);
        *reinterpret_cast<uint2*>(reinterpret_cast<unsigned short*>(outb) + base + tid*4) = ob.u2;
    }
}

// ---------------- launch ----------------
extern "C" void kernel_launch(void* const* d_in, const int* in_sizes, int n_in,
                              void* d_out, int out_size, void* d_ws, size_t ws_size,
                              hipStream_t stream) {
    const float* x   = (const float*)d_in[0];
    const float* Wq  = (const float*)d_in[1];
    const float* Wk  = (const float*)d_in[2];
    const float* Wv  = (const float*)d_in[3];
    const float* Wo  = (const float*)d_in[4];
    const float* W1  = (const float*)d_in[5];
    const float* b1  = (const float*)d_in[6];
    const float* W2  = (const float*)d_in[7];
    const float* b2  = (const float*)d_in[8];
    const float* gain1 = (const float*)d_in[9];
    const float* bias1 = (const float*)d_in[10];
    const float* gain2 = (const float*)d_in[11];
    const float* bias2 = (const float*)d_in[12];

    char* ws = (char*)d_ws;
    __hip_bfloat16* Wqkv_t = (__hip_bfloat16*)(ws + 0);          // 3072x1024
    __hip_bfloat16* Wo_t   = (__hip_bfloat16*)(ws + 6291456);    // 1024x1024
    __hip_bfloat16* W1_t   = (__hip_bfloat16*)(ws + 8388608);    // 4096x1024
    __hip_bfloat16* W2_t   = (__hip_bfloat16*)(ws + 16777216);   // 1024x4096
    __hip_bfloat16* xb     = (__hip_bfloat16*)(ws + 25165824);   // 8192x1024
    __hip_bfloat16* qb     = (__hip_bfloat16*)(ws + 41943040);   // 64x2048x64
    __hip_bfloat16* kb     = (__hip_bfloat16*)(ws + 58720256);
    __hip_bfloat16* vtb    = (__hip_bfloat16*)(ws + 75497472);   // 64x64x2048
    __hip_bfloat16* h1     = (__hip_bfloat16*)(ws + 25165824);   // reuse xb..vt, 8192x4096
    __hip_bfloat16* mergedb= (__hip_bfloat16*)(ws + 92274688);   // 8192x1024
    float*          attended=(float*)(ws + 109051904);           // 8192x1024 f32
    float*          ff     = (float*)(ws + 92274688);            // reuse merged+attended
    float*          x1f    = (float*)(ws + 142606336);           // 8192x1024 f32
    __hip_bfloat16* x1b    = (__hip_bfloat16*)(ws + 176160768);  // 8192x1024
    float*          outf   = (float*)d_out;

    dim3 tb(32,8);
    // weight transposes (fp32 -> bf16, N x K)
    transpose_cvt<<<dim3(32,32),  tb, 0, stream>>>(Wq, Wqkv_t,                 1024, 1024);
    transpose_cvt<<<dim3(32,32),  tb, 0, stream>>>(Wk, Wqkv_t + 1024*1024,     1024, 1024);
    transpose_cvt<<<dim3(32,32),  tb, 0, stream>>>(Wv, Wqkv_t + 2*1024*1024,   1024, 1024);
    transpose_cvt<<<dim3(32,32),  tb, 0, stream>>>(Wo, Wo_t,                   1024, 1024);
    transpose_cvt<<<dim3(128,32), tb, 0, stream>>>(W1, W1_t,                   1024, 4096);
    transpose_cvt<<<dim3(32,128), tb, 0, stream>>>(W2, W2_t,                   4096, 1024);
    // x -> bf16
    cvt_bf16<<<(MROWS*EMB/4 + 255)/256, 256, 0, stream>>>(x, xb, MROWS*EMB/4);

    // QKV projection (fused)
    gemm_bt<0><<<dim3(MROWS/128, 3072/128), 256, 0, stream>>>(
        xb, Wqkv_t, MROWS, 3072, EMB, nullptr, nullptr, nullptr, qb, kb, vtb);
    // attention
    attn_fwd<<<dim3(TSEQ/64, BATCH*HEADS), 256, 0, stream>>>(qb, kb, vtb, mergedb);
    // output projection
    gemm_bt<1><<<dim3(MROWS/128, EMB/128), 256, 0, stream>>>(
        mergedb, Wo_t, MROWS, EMB, EMB, attended, nullptr, nullptr, nullptr, nullptr, nullptr);
    // residual + LN1
    ln_res<<<MROWS, 256, 0, stream>>>(attended, x, gain1, bias1, x1f, x1b);
    // FF1: relu(x1 @ W1 + b1) -> bf16
    gemm_bt<2><<<dim3(MROWS/128, DIM_FF/128), 256, 0, stream>>>(
        x1b, W1_t, MROWS, DIM_FF, EMB, nullptr, h1, b1, nullptr, nullptr, nullptr);
    // FF2: h1 @ W2 + b2 -> f32
    gemm_bt<3><<<dim3(MROWS/128, EMB/128), 256, 0, stream>>>(
        h1, W2_t, MROWS, EMB, DIM_FF, ff, nullptr, b2, nullptr, nullptr, nullptr);
    // residual + LN2 -> out
    ln_res<<<MROWS, 256, 0, stream>>>(ff, x1f, gain2, bias2, outf, nullptr);
}

// Round 2
// 829.143 us; speedup vs baseline: 1.0078x; 1.0078x over previous
//
#include <hip/hip_runtime.h>
#include <hip/hip_bf16.h>
#include <math.h>

#define EMB 1024
#define DIM_FF 4096
#define HEADS 16
#define HD 64
#define TSEQ 2048
#define BATCH 4
#define MROWS (BATCH*TSEQ)
#define LN_EPS 1e-5f

typedef __attribute__((ext_vector_type(8))) short short8;
typedef __attribute__((ext_vector_type(4))) float f32x4;

#define MFMA16(a,b,c) __builtin_amdgcn_mfma_f32_16x16x32_bf16((a),(b),(c),0,0,0)

#define GLOBAL_AS(p) ((const __attribute__((address_space(1))) void*)(p))
#define LDS_AS(p)    ((__attribute__((address_space(3))) void*)(p))

__device__ __forceinline__ unsigned short bf16bits(float f){
    __hip_bfloat16 h = __float2bfloat16(f);
    unsigned short u;
    __builtin_memcpy(&u, &h, 2);
    return u;
}

// ---------------- convert fp32 -> bf16 (row-major) ----------------
__global__ __launch_bounds__(256)
void cvt_bf16(const float* __restrict__ in, __hip_bfloat16* __restrict__ out, int n4){
    int i = blockIdx.x*256 + threadIdx.x;
    if (i >= n4) return;
    f32x4 v = reinterpret_cast<const f32x4*>(in)[i];
    union { unsigned short us[4]; uint2 u2; } o;
    #pragma unroll
    for (int j=0;j<4;++j) o.us[j] = bf16bits(v[j]);
    *reinterpret_cast<uint2*>(reinterpret_cast<unsigned short*>(out) + (size_t)i*4) = o.u2;
}

// ---------------- transpose + convert: in (R x C) fp32 -> out (C x R) bf16 ----------------
__global__ __launch_bounds__(256)
void transpose_cvt(const float* __restrict__ in, __hip_bfloat16* __restrict__ out, int R, int C){
    __shared__ __hip_bfloat16 tile[32][33];
    int bx = blockIdx.x*32;  // col base
    int by = blockIdx.y*32;  // row base
    int x = bx + threadIdx.x;
    #pragma unroll
    for (int i = threadIdx.y; i < 32; i += 8){
        tile[i][threadIdx.x] = __float2bfloat16(in[(size_t)(by+i)*C + x]);
    }
    __syncthreads();
    int xo = by + threadIdx.x; // new col = old row
    #pragma unroll
    for (int i = threadIdx.y; i < 32; i += 8){
        out[(size_t)(bx+i)*R + xo] = tile[threadIdx.x][i];
    }
}

// ---------------- GEMM: C[M,N] = A[M,K](bf16) * Bt[N,K](bf16)^T ----------------
// Staging via global_load_lds width=16 (m97 structure, linear LDS).
// EPI: 0 = QKV scatter, 1 = f32 out, 2 = +bias,relu -> bf16, 3 = +bias -> f32
template<int EPI>
__global__ __launch_bounds__(256, 2)
void gemm_bt(const __hip_bfloat16* __restrict__ A,
             const __hip_bfloat16* __restrict__ Bt,
             int M, int N, int K,
             float* __restrict__ Cf,
             __hip_bfloat16* __restrict__ Cb,
             const float* __restrict__ bias,
             __hip_bfloat16* __restrict__ qo,
             __hip_bfloat16* __restrict__ ko,
             __hip_bfloat16* __restrict__ vto)
{
    __shared__ __align__(16) __hip_bfloat16 As[128*32];
    __shared__ __align__(16) __hip_bfloat16 Bs[128*32];
    const int tid = threadIdx.x;
    const int lane = tid & 63;
    const int wid = tid >> 6;
    const int wm = wid >> 1, wn = wid & 1;
    const int row0 = blockIdx.x * 128;
    const int col0 = blockIdx.y * 128;
    const int rA = lane & 15, kg = lane >> 4;

    // staging: wave w stages rows [w*32, w*32+32) of As and Bs.
    // HW writes LDS at (uniform base) + lane*16B; lane l covers row l>>2, elems (l&3)*8.
    const int lrow = lane >> 2;
    const int lcol = (lane & 3) << 3;

    f32x4 acc[4][4] = {};

    for (int kt = 0; kt < K; kt += 32) {
        __syncthreads();
        #pragma unroll
        for (int half = 0; half < 2; ++half) {
            const int rbase = (wid << 5) + (half << 4);
            const int r = rbase + lrow;
            __builtin_amdgcn_global_load_lds(
                GLOBAL_AS(A + (size_t)(row0 + r)*K + kt + lcol),
                LDS_AS(&As[rbase*32]), 16, 0, 0);
            __builtin_amdgcn_global_load_lds(
                GLOBAL_AS(Bt + (size_t)(col0 + r)*K + kt + lcol),
                LDS_AS(&Bs[rbase*32]), 16, 0, 0);
        }
        __syncthreads();
        short8 af[4], bfr[4];
        #pragma unroll
        for (int mi = 0; mi < 4; ++mi)
            af[mi] = *reinterpret_cast<const short8*>(&As[(wm*64 + mi*16 + rA)*32 + (kg<<3)]);
        #pragma unroll
        for (int ni = 0; ni < 4; ++ni)
            bfr[ni] = *reinterpret_cast<const short8*>(&Bs[(wn*64 + ni*16 + rA)*32 + (kg<<3)]);
        #pragma unroll
        for (int mi = 0; mi < 4; ++mi)
            #pragma unroll
            for (int ni = 0; ni < 4; ++ni)
                acc[mi][ni] = MFMA16(af[mi], bfr[ni], acc[mi][ni]);
    }

    #pragma unroll
    for (int mi=0; mi<4; ++mi) {
        #pragma unroll
        for (int ni=0; ni<4; ++ni) {
            #pragma unroll
            for (int j=0;j<4;++j){
                float v = acc[mi][ni][j];
                int grow = row0 + wm*64 + mi*16 + (kg<<2) + j;
                int gcol = col0 + wn*64 + ni*16 + rA;
                if constexpr (EPI==0) {
                    int b = grow >> 11, t = grow & 2047;
                    int which = gcol >> 10, hdx = gcol & 1023;
                    int h = hdx >> 6, d = hdx & 63;
                    int bh = b*HEADS + h;
                    __hip_bfloat16 bv = __float2bfloat16(v);
                    if (which==0)      qo[((size_t)bh*TSEQ + t)*HD + d] = bv;
                    else if (which==1) ko[((size_t)bh*TSEQ + t)*HD + d] = bv;
                    else               vto[((size_t)bh*HD + d)*TSEQ + t] = bv;
                } else if constexpr (EPI==1) {
                    Cf[(size_t)grow*N + gcol] = v;
                } else if constexpr (EPI==2) {
                    v += bias[gcol]; v = v > 0.0f ? v : 0.0f;
                    Cb[(size_t)grow*N + gcol] = __float2bfloat16(v);
                } else {
                    Cf[(size_t)grow*N + gcol] = v + bias[gcol];
                }
            }
        }
    }
}

// ---------------- flash attention (swapped QK^T, lane-local softmax, no barriers) ----------------
// q,k: [BH][T][64] bf16 ; vt: [BH][64][T] bf16 ; merged: [B*T][1024] bf16
// Per wave: 16 q-rows. S^T = mfma(K,Q): lane (rA,kg) holds 16 scores of q-row rA
// at k = kt + kb*16 + kg*4 + j. Row-reduce = in-lane tree + shfl_xor(16,32).
__global__ __launch_bounds__(256, 2)
void attn_fwd(const __hip_bfloat16* __restrict__ q,
              const __hip_bfloat16* __restrict__ k,
              const __hip_bfloat16* __restrict__ vt,
              __hip_bfloat16* __restrict__ merged)
{
    const int bh = blockIdx.y;
    const int wid = threadIdx.x >> 6, lane = threadIdx.x & 63;
    const int rA = lane & 15, kg = lane >> 4;
    const int qrow0 = blockIdx.x*64 + wid*16;
    const __hip_bfloat16* Qh = q  + (size_t)bh*TSEQ*HD;
    const __hip_bfloat16* Kh = k  + (size_t)bh*TSEQ*HD;
    const __hip_bfloat16* Vh = vt + (size_t)bh*HD*TSEQ;
    // per-wave P buffer, k-group-major: [wave][kgroup g=k/8][q][k%8]
    __shared__ __align__(16) __hip_bfloat16 plds[4][8][16][8];

    short8 aQ0 = *reinterpret_cast<const short8*>(Qh + (size_t)(qrow0+rA)*HD + (kg<<3));
    short8 aQ1 = *reinterpret_cast<const short8*>(Qh + (size_t)(qrow0+rA)*HD + 32 + (kg<<3));

    f32x4 O[4] = {};
    float m = -1e30f, l = 0.f;

    for (int kt=0; kt<TSEQ; kt+=64) {
        // S^T tiles: st[kb][j] = S[k = kt+kb*16+kg*4+j][q = rA]  (unscaled)
        f32x4 st[4];
        #pragma unroll
        for (int kb=0; kb<4; ++kb) {
            const __hip_bfloat16* Kb = Kh + (size_t)(kt + kb*16 + rA)*HD + (kg<<3);
            short8 aK0 = *reinterpret_cast<const short8*>(Kb);
            short8 aK1 = *reinterpret_cast<const short8*>(Kb + 32);
            f32x4 z = {};
            z = MFMA16(aK0, aQ0, z);
            st[kb] = MFMA16(aK1, aQ1, z);
        }
        // online softmax (per lane: q-row rA, replicated across kg groups)
        f32x4 sm01, sm;
        #pragma unroll
        for (int j=0;j<4;++j) sm01[j] = fmaxf(st[0][j], st[1][j]);
        #pragma unroll
        for (int j=0;j<4;++j) sm[j] = fmaxf(sm01[j], fmaxf(st[2][j], st[3][j]));
        float mx = fmaxf(fmaxf(sm[0], sm[1]), fmaxf(sm[2], sm[3]));
        mx = fmaxf(mx, __shfl_xor(mx, 16));
        mx = fmaxf(mx, __shfl_xor(mx, 32));
        float mn = fmaxf(m, mx*0.125f);
        float al = __expf(m - mn);
        f32x4 ps[4];
        #pragma unroll
        for (int kb=0; kb<4; ++kb)
            #pragma unroll
            for (int j=0;j<4;++j)
                ps[kb][j] = __expf(fmaf(st[kb][j], 0.125f, -mn));
        f32x4 ssv = (ps[0]+ps[1]) + (ps[2]+ps[3]);
        float rs = (ssv[0]+ssv[1]) + (ssv[2]+ssv[3]);
        rs += __shfl_xor(rs, 16);
        rs += __shfl_xor(rs, 32);
        l = l*al + rs; m = mn;
        // rescale O: O row = kg*4+j needs alpha of that q-row (held by lane kg*4+j)
        float alq[4];
        #pragma unroll
        for (int j=0;j<4;++j) alq[j] = __shfl(al, (kg<<2)+j);
        #pragma unroll
        for (int dt=0; dt<4; ++dt)
            #pragma unroll
            for (int j=0;j<4;++j) O[dt][j] *= alq[j];
        // pack P (bf16) to per-wave LDS, k-group-major
        #pragma unroll
        for (int kb=0; kb<4; ++kb) {
            uint2 w;
            w.x = (unsigned)bf16bits(ps[kb][0]) | ((unsigned)bf16bits(ps[kb][1]) << 16);
            w.y = (unsigned)bf16bits(ps[kb][2]) | ((unsigned)bf16bits(ps[kb][3]) << 16);
            // k = kb*16 + kg*4 + j -> group g = 2*kb + (kg>>1), elem (kg&1)*4 + j
            *reinterpret_cast<uint2*>(&plds[wid][2*kb + (kg>>1)][rA][(kg&1)<<2]) = w;
        }
        // PV: A-fragment of P from LDS, B = V^T rows (d), contraction over k
        short8 aP0 = *reinterpret_cast<const short8*>(&plds[wid][kg][rA][0]);
        short8 aP1 = *reinterpret_cast<const short8*>(&plds[wid][4+kg][rA][0]);
        #pragma unroll
        for (int dt=0; dt<4; ++dt) {
            const __hip_bfloat16* Vb = Vh + (size_t)(dt*16+rA)*TSEQ + kt + (kg<<3);
            short8 bV0 = *reinterpret_cast<const short8*>(Vb);
            short8 bV1 = *reinterpret_cast<const short8*>(Vb + 32);
            O[dt] = MFMA16(aP0, bV0, O[dt]);
            O[dt] = MFMA16(aP1, bV1, O[dt]);
        }
    }
    float lq[4];
    #pragma unroll
    for (int j=0;j<4;++j) lq[j] = 1.0f / __shfl(l, (kg<<2)+j);
    const int b = bh >> 4, h = bh & 15;
    #pragma unroll
    for (int dt=0; dt<4; ++dt){
        #pragma unroll
        for (int j=0;j<4;++j){
            int t = qrow0 + (kg<<2) + j;
            int col = h*HD + dt*16 + rA;
            merged[((size_t)(b*TSEQ + t))*EMB + col] = __float2bfloat16(O[dt][j]*lq[j]);
        }
    }
}

// ---------------- residual + layer norm ----------------
__global__ __launch_bounds__(256)
void ln_res(const float* __restrict__ a, const float* __restrict__ res,
            const float* __restrict__ gain, const float* __restrict__ bias,
            float* __restrict__ outf, __hip_bfloat16* __restrict__ outb)
{
    const int row = blockIdx.x;
    const int tid = threadIdx.x;
    const int lane = tid & 63, wid = tid >> 6;
    const size_t base = (size_t)row * EMB;
    f32x4 va = *reinterpret_cast<const f32x4*>(a + base + tid*4);
    f32x4 vr = *reinterpret_cast<const f32x4*>(res + base + tid*4);
    f32x4 v = va + vr;
    float s = v[0]+v[1]+v[2]+v[3];
    #pragma unroll
    for (int off=1; off<64; off<<=1) s += __shfl_xor(s, off);
    __shared__ float red1[4], red2[4];
    if (lane==0) red1[wid] = s;
    __syncthreads();
    float mean = (red1[0]+red1[1]+red1[2]+red1[3]) * (1.0f/EMB);
    f32x4 d;
    #pragma unroll
    for (int j=0;j<4;++j) d[j] = v[j] - mean;
    float qs = d[0]*d[0]+d[1]*d[1]+d[2]*d[2]+d[3]*d[3];
    #pragma unroll
    for (int off=1; off<64; off<<=1) qs += __shfl_xor(qs, off);
    if (lane==0) red2[wid] = qs;
    __syncthreads();
    float var = (red2[0]+red2[1]+red2[2]+red2[3]) * (1.0f/EMB);
    float r = 1.0f/(sqrtf(var)+LN_EPS);
    f32x4 g = *reinterpret_cast<const f32x4*>(gain + tid*4);
    f32x4 bb = *reinterpret_cast<const f32x4*>(bias + tid*4);
    f32x4 o;
    #pragma unroll
    for (int j=0;j<4;++j) o[j] = g[j]*(d[j]*r) + bb[j];
    *reinterpret_cast<f32x4*>(outf + base + tid*4) = o;
    if (outb) {
        union { unsigned short us[4]; uint2 u2; } ob;
        #pragma unroll
        for (int j=0;j<4;++j) ob.us[j] = bf16bits(o[j]);
        *reinterpret_cast<uint2*>(reinterpret_cast<unsigned short*>(outb) + base + tid*4) = ob.u2;
    }
}

// ---------------- launch ----------------
extern "C" void kernel_launch(void* const* d_in, const int* in_sizes, int n_in,
                              void* d_out, int out_size, void* d_ws, size_t ws_size,
                              hipStream_t stream) {
    const float* x   = (const float*)d_in[0];
    const float* Wq  = (const float*)d_in[1];
    const float* Wk  = (const float*)d_in[2];
    const float* Wv  = (const float*)d_in[3];
    const float* Wo  = (const float*)d_in[4];
    const float* W1  = (const float*)d_in[5];
    const float* b1  = (const float*)d_in[6];
    const float* W2  = (const float*)d_in[7];
    const float* b2  = (const float*)d_in[8];
    const float* gain1 = (const float*)d_in[9];
    const float* bias1 = (const float*)d_in[10];
    const float* gain2 = (const float*)d_in[11];
    const float* bias2 = (const float*)d_in[12];

    char* ws = (char*)d_ws;
    __hip_bfloat16* Wqkv_t = (__hip_bfloat16*)(ws + 0);          // 3072x1024
    __hip_bfloat16* Wo_t   = (__hip_bfloat16*)(ws + 6291456);    // 1024x1024
    __hip_bfloat16* W1_t   = (__hip_bfloat16*)(ws + 8388608);    // 4096x1024
    __hip_bfloat16* W2_t   = (__hip_bfloat16*)(ws + 16777216);   // 1024x4096
    __hip_bfloat16* xb     = (__hip_bfloat16*)(ws + 25165824);   // 8192x1024
    __hip_bfloat16* qb     = (__hip_bfloat16*)(ws + 41943040);   // 64x2048x64
    __hip_bfloat16* kb     = (__hip_bfloat16*)(ws + 58720256);
    __hip_bfloat16* vtb    = (__hip_bfloat16*)(ws + 75497472);   // 64x64x2048
    __hip_bfloat16* h1     = (__hip_bfloat16*)(ws + 25165824);   // reuse xb..vt, 8192x4096
    __hip_bfloat16* mergedb= (__hip_bfloat16*)(ws + 92274688);   // 8192x1024
    float*          attended=(float*)(ws + 109051904);           // 8192x1024 f32
    float*          ff     = (float*)(ws + 92274688);            // reuse merged+attended
    float*          x1f    = (float*)(ws + 142606336);           // 8192x1024 f32
    __hip_bfloat16* x1b    = (__hip_bfloat16*)(ws + 176160768);  // 8192x1024
    float*          outf   = (float*)d_out;

    dim3 tb(32,8);
    // weight transposes (fp32 -> bf16, N x K)
    transpose_cvt<<<dim3(32,32),  tb, 0, stream>>>(Wq, Wqkv_t,                 1024, 1024);
    transpose_cvt<<<dim3(32,32),  tb, 0, stream>>>(Wk, Wqkv_t + 1024*1024,     1024, 1024);
    transpose_cvt<<<dim3(32,32),  tb, 0, stream>>>(Wv, Wqkv_t + 2*1024*1024,   1024, 1024);
    transpose_cvt<<<dim3(32,32),  tb, 0, stream>>>(Wo, Wo_t,                   1024, 1024);
    transpose_cvt<<<dim3(128,32), tb, 0, stream>>>(W1, W1_t,                   1024, 4096);
    transpose_cvt<<<dim3(32,128), tb, 0, stream>>>(W2, W2_t,                   4096, 1024);
    // x -> bf16
    cvt_bf16<<<(MROWS*EMB/4 + 255)/256, 256, 0, stream>>>(x, xb, MROWS*EMB/4);

    // QKV projection (fused)
    gemm_bt<0><<<dim3(MROWS/128, 3072/128), 256, 0, stream>>>(
        xb, Wqkv_t, MROWS, 3072, EMB, nullptr, nullptr, nullptr, qb, kb, vtb);
    // attention
    attn_fwd<<<dim3(TSEQ/64, BATCH*HEADS), 256, 0, stream>>>(qb, kb, vtb, mergedb);
    // output projection
    gemm_bt<1><<<dim3(MROWS/128, EMB/128), 256, 0, stream>>>(
        mergedb, Wo_t, MROWS, EMB, EMB, attended, nullptr, nullptr, nullptr, nullptr, nullptr);
    // residual + LN1
    ln_res<<<MROWS, 256, 0, stream>>>(attended, x, gain1, bias1, x1f, x1b);
    // FF1: relu(x1 @ W1 + b1) -> bf16
    gemm_bt<2><<<dim3(MROWS/128, DIM_FF/128), 256, 0, stream>>>(
        x1b, W1_t, MROWS, DIM_FF, EMB, nullptr, h1, b1, nullptr, nullptr, nullptr);
    // FF2: h1 @ W2 + b2 -> f32
    gemm_bt<3><<<dim3(MROWS/128, EMB/128), 256, 0, stream>>>(
        h1, W2_t, MROWS, EMB, DIM_FF, ff, nullptr, b2, nullptr, nullptr, nullptr);
    // residual + LN2 -> out
    ln_res<<<MROWS, 256, 0, stream>>>(ff, x1f, gain2, bias2, outf, nullptr);
}

// Round 3
// 486.859 us; speedup vs baseline: 1.7163x; 1.7030x over previous
//
#include <hip/hip_runtime.h>
#include <hip/hip_bf16.h>
#include <math.h>

#define EMB 1024
#define DIM_FF 4096
#define HEADS 16
#define HD 64
#define TSEQ 2048
#define BATCH 4
#define MROWS (BATCH*TSEQ)
#define LN_EPS 1e-5f

typedef __attribute__((ext_vector_type(8))) short short8;
typedef __attribute__((ext_vector_type(4))) float f32x4;

#define MFMA16(a,b,c) __builtin_amdgcn_mfma_f32_16x16x32_bf16((a),(b),(c),0,0,0)

#define GLOBAL_AS(p) ((const __attribute__((address_space(1))) void*)(p))
#define LDS_AS(p)    ((__attribute__((address_space(3))) void*)(p))

__device__ __forceinline__ unsigned short bf16bits(float f){
    __hip_bfloat16 h = __float2bfloat16(f);
    unsigned short u;
    __builtin_memcpy(&u, &h, 2);
    return u;
}

// ---------------- convert fp32 -> bf16 (row-major) ----------------
__global__ __launch_bounds__(256)
void cvt_bf16(const float* __restrict__ in, __hip_bfloat16* __restrict__ out, int n4){
    int i = blockIdx.x*256 + threadIdx.x;
    if (i >= n4) return;
    f32x4 v = reinterpret_cast<const f32x4*>(in)[i];
    union { unsigned short us[4]; uint2 u2; } o;
    #pragma unroll
    for (int j=0;j<4;++j) o.us[j] = bf16bits(v[j]);
    *reinterpret_cast<uint2*>(reinterpret_cast<unsigned short*>(out) + (size_t)i*4) = o.u2;
}

// ---------------- transpose + convert: in (R x C) fp32 -> out (C x R) bf16 ----------------
__global__ __launch_bounds__(256)
void transpose_cvt(const float* __restrict__ in, __hip_bfloat16* __restrict__ out, int R, int C){
    __shared__ __hip_bfloat16 tile[32][33];
    int bx = blockIdx.x*32;  // col base
    int by = blockIdx.y*32;  // row base
    int x = bx + threadIdx.x;
    #pragma unroll
    for (int i = threadIdx.y; i < 32; i += 8){
        tile[i][threadIdx.x] = __float2bfloat16(in[(size_t)(by+i)*C + x]);
    }
    __syncthreads();
    int xo = by + threadIdx.x; // new col = old row
    #pragma unroll
    for (int i = threadIdx.y; i < 32; i += 8){
        out[(size_t)(bx+i)*R + xo] = tile[threadIdx.x][i];
    }
}

// ---------------- GEMM: C[M,N] = A[M,K](bf16) * Bt[N,K](bf16)^T ----------------
// Staging via global_load_lds width=16 (m97 structure, linear LDS).
// EPI: 0 = QKV scatter, 1 = f32 out, 2 = +bias,relu -> bf16, 3 = +bias -> f32
template<int EPI>
__global__ __launch_bounds__(256, 2)
void gemm_bt(const __hip_bfloat16* __restrict__ A,
             const __hip_bfloat16* __restrict__ Bt,
             int M, int N, int K,
             float* __restrict__ Cf,
             __hip_bfloat16* __restrict__ Cb,
             const float* __restrict__ bias,
             __hip_bfloat16* __restrict__ qo,
             __hip_bfloat16* __restrict__ ko,
             __hip_bfloat16* __restrict__ vto)
{
    __shared__ __align__(16) __hip_bfloat16 As[128*32];
    __shared__ __align__(16) __hip_bfloat16 Bs[128*32];
    const int tid = threadIdx.x;
    const int lane = tid & 63;
    const int wid = tid >> 6;
    const int wm = wid >> 1, wn = wid & 1;
    const int row0 = blockIdx.x * 128;
    const int col0 = blockIdx.y * 128;
    const int rA = lane & 15, kg = lane >> 4;

    const int lrow = lane >> 2;
    const int lcol = (lane & 3) << 3;

    f32x4 acc[4][4] = {};

    for (int kt = 0; kt < K; kt += 32) {
        __syncthreads();
        #pragma unroll
        for (int half = 0; half < 2; ++half) {
            const int rbase = (wid << 5) + (half << 4);
            const int r = rbase + lrow;
            __builtin_amdgcn_global_load_lds(
                GLOBAL_AS(A + (size_t)(row0 + r)*K + kt + lcol),
                LDS_AS(&As[rbase*32]), 16, 0, 0);
            __builtin_amdgcn_global_load_lds(
                GLOBAL_AS(Bt + (size_t)(col0 + r)*K + kt + lcol),
                LDS_AS(&Bs[rbase*32]), 16, 0, 0);
        }
        __syncthreads();
        short8 af[4], bfr[4];
        #pragma unroll
        for (int mi = 0; mi < 4; ++mi)
            af[mi] = *reinterpret_cast<const short8*>(&As[(wm*64 + mi*16 + rA)*32 + (kg<<3)]);
        #pragma unroll
        for (int ni = 0; ni < 4; ++ni)
            bfr[ni] = *reinterpret_cast<const short8*>(&Bs[(wn*64 + ni*16 + rA)*32 + (kg<<3)]);
        #pragma unroll
        for (int mi = 0; mi < 4; ++mi)
            #pragma unroll
            for (int ni = 0; ni < 4; ++ni)
                acc[mi][ni] = MFMA16(af[mi], bfr[ni], acc[mi][ni]);
    }

    #pragma unroll
    for (int mi=0; mi<4; ++mi) {
        #pragma unroll
        for (int ni=0; ni<4; ++ni) {
            #pragma unroll
            for (int j=0;j<4;++j){
                float v = acc[mi][ni][j];
                int grow = row0 + wm*64 + mi*16 + (kg<<2) + j;
                int gcol = col0 + wn*64 + ni*16 + rA;
                if constexpr (EPI==0) {
                    int b = grow >> 11, t = grow & 2047;
                    int which = gcol >> 10, hdx = gcol & 1023;
                    int h = hdx >> 6, d = hdx & 63;
                    int bh = b*HEADS + h;
                    __hip_bfloat16 bv = __float2bfloat16(v);
                    if (which==0)      qo[((size_t)bh*TSEQ + t)*HD + d] = bv;
                    else if (which==1) ko[((size_t)bh*TSEQ + t)*HD + d] = bv;
                    else               vto[((size_t)bh*HD + d)*TSEQ + t] = bv;
                } else if constexpr (EPI==1) {
                    Cf[(size_t)grow*N + gcol] = v;
                } else if constexpr (EPI==2) {
                    v += bias[gcol]; v = v > 0.0f ? v : 0.0f;
                    Cb[(size_t)grow*N + gcol] = __float2bfloat16(v);
                } else {
                    Cf[(size_t)grow*N + gcol] = v + bias[gcol];
                }
            }
        }
    }
}

// ---------------- flash attention ----------------
// Swapped QK^T + lane-local softmax; K/V staged to LDS (double-buffered) via
// global_load_lds with pre-swizzled SOURCE (phys slot = logical slot ^ (row&7)),
// shared by all 4 waves; 1 barrier per KV tile.
// q,k: [BH][T][64] bf16 ; vt: [BH][64][T] bf16 ; merged: [B*T][1024] bf16
__global__ __launch_bounds__(256, 4)
void attn_fwd(const __hip_bfloat16* __restrict__ q,
              const __hip_bfloat16* __restrict__ k,
              const __hip_bfloat16* __restrict__ vt,
              __hip_bfloat16* __restrict__ merged)
{
    // bijective XCD swizzle: 2048 blocks, 8 XCDs, 256-contiguous chunk each
    const int wg = (blockIdx.x & 7) * 256 + (blockIdx.x >> 3);
    const int bh = wg >> 5;          // 0..63
    const int qt = wg & 31;          // q-tile 0..31
    const int wid = threadIdx.x >> 6, lane = threadIdx.x & 63;
    const int rA = lane & 15, kg = lane >> 4;
    const int qrow0 = qt*64 + wid*16;
    const __hip_bfloat16* Qh = q  + (size_t)bh*TSEQ*HD;
    const __hip_bfloat16* Kh = k  + (size_t)bh*TSEQ*HD;
    const __hip_bfloat16* Vh = vt + (size_t)bh*HD*TSEQ;

    __shared__ __align__(16) __hip_bfloat16 Kl[2][64*64];
    __shared__ __align__(16) __hip_bfloat16 Vl[2][64*64];
    __shared__ __align__(16) __hip_bfloat16 plds[4][8][16][8];

    short8 aQ0 = *reinterpret_cast<const short8*>(Qh + (size_t)(qrow0+rA)*HD + (kg<<3));
    short8 aQ1 = *reinterpret_cast<const short8*>(Qh + (size_t)(qrow0+rA)*HD + 32 + (kg<<3));

    // staging geometry: wave wid stages rows [wid*16, wid*16+16) of K and V tiles.
    // lane l covers row rbase+(l>>3), logical slot (l&7)^(l>>3)  (pre-swizzled source)
    const int lrow = lane >> 3;
    const int lslot = ((lane & 7) ^ lrow) << 3;
    const __hip_bfloat16* sK0 = Kh + (size_t)(wid*16 + lrow)*HD + lslot;
    const __hip_bfloat16* sV0 = Vh + (size_t)(wid*16 + lrow)*TSEQ + lslot;
    const int dOff = wid*16*64;

    f32x4 O[4] = {};
    float m = -1e30f, l = 0.f;
    const int swz = rA & 7;

    // prologue: stage tile 0 into buf 0
    {
        __builtin_amdgcn_global_load_lds(GLOBAL_AS(sK0),          LDS_AS(&Kl[0][dOff]),        16, 0, 0);
        __builtin_amdgcn_global_load_lds(GLOBAL_AS(sK0 + 8*HD),   LDS_AS(&Kl[0][dOff + 8*64]), 16, 0, 0);
        __builtin_amdgcn_global_load_lds(GLOBAL_AS(sV0),          LDS_AS(&Vl[0][dOff]),        16, 0, 0);
        __builtin_amdgcn_global_load_lds(GLOBAL_AS(sV0 + 8*TSEQ), LDS_AS(&Vl[0][dOff + 8*64]), 16, 0, 0);
    }
    __syncthreads();

    for (int t = 0; t < TSEQ/64; ++t) {
        const int b = t & 1;
        if (t < TSEQ/64 - 1) {
            const int kt = (t+1)*64;
            __builtin_amdgcn_global_load_lds(GLOBAL_AS(sK0 + (size_t)kt*HD),          LDS_AS(&Kl[b^1][dOff]),        16, 0, 0);
            __builtin_amdgcn_global_load_lds(GLOBAL_AS(sK0 + (size_t)(kt+8)*HD),      LDS_AS(&Kl[b^1][dOff + 8*64]), 16, 0, 0);
            __builtin_amdgcn_global_load_lds(GLOBAL_AS(sV0 + kt),                     LDS_AS(&Vl[b^1][dOff]),        16, 0, 0);
            __builtin_amdgcn_global_load_lds(GLOBAL_AS(sV0 + 8*TSEQ + kt),            LDS_AS(&Vl[b^1][dOff + 8*64]), 16, 0, 0);
        }
        const char* Kb = (const char*)&Kl[b][0];
        const char* Vb = (const char*)&Vl[b][0];

        // S^T tiles: st[kb][j] = S[k = kb*16+kg*4+j][q = rA]  (unscaled)
        f32x4 st[4];
        #pragma unroll
        for (int kb = 0; kb < 4; ++kb) {
            const int ro = (kb*16 + rA) * 128;
            short8 aK0 = *reinterpret_cast<const short8*>(Kb + ro + ((kg ^ swz) << 4));
            short8 aK1 = *reinterpret_cast<const short8*>(Kb + ro + (((4+kg) ^ swz) << 4));
            f32x4 z = {};
            z = MFMA16(aK0, aQ0, z);
            st[kb] = MFMA16(aK1, aQ1, z);
        }
        // online softmax (per lane: q-row rA, replicated across kg groups)
        f32x4 sm01, sm;
        #pragma unroll
        for (int j=0;j<4;++j) sm01[j] = fmaxf(st[0][j], st[1][j]);
        #pragma unroll
        for (int j=0;j<4;++j) sm[j] = fmaxf(sm01[j], fmaxf(st[2][j], st[3][j]));
        float mx = fmaxf(fmaxf(sm[0], sm[1]), fmaxf(sm[2], sm[3]));
        mx = fmaxf(mx, __shfl_xor(mx, 16));
        mx = fmaxf(mx, __shfl_xor(mx, 32));
        float mn = fmaxf(m, mx*0.125f);
        float al = __expf(m - mn);
        f32x4 ps[4];
        #pragma unroll
        for (int kb=0; kb<4; ++kb)
            #pragma unroll
            for (int j=0;j<4;++j)
                ps[kb][j] = __expf(fmaf(st[kb][j], 0.125f, -mn));
        f32x4 ssv = (ps[0]+ps[1]) + (ps[2]+ps[3]);
        float rs = (ssv[0]+ssv[1]) + (ssv[2]+ssv[3]);
        rs += __shfl_xor(rs, 16);
        rs += __shfl_xor(rs, 32);
        l = l*al + rs; m = mn;
        float alq[4];
        #pragma unroll
        for (int j=0;j<4;++j) alq[j] = __shfl(al, (kg<<2)+j);
        #pragma unroll
        for (int dt=0; dt<4; ++dt)
            #pragma unroll
            for (int j=0;j<4;++j) O[dt][j] *= alq[j];
        // pack P (bf16) to per-wave LDS, k-group-major
        #pragma unroll
        for (int kb=0; kb<4; ++kb) {
            uint2 w;
            w.x = (unsigned)bf16bits(ps[kb][0]) | ((unsigned)bf16bits(ps[kb][1]) << 16);
            w.y = (unsigned)bf16bits(ps[kb][2]) | ((unsigned)bf16bits(ps[kb][3]) << 16);
            *reinterpret_cast<uint2*>(&plds[wid][2*kb + (kg>>1)][rA][(kg&1)<<2]) = w;
        }
        short8 aP0 = *reinterpret_cast<const short8*>(&plds[wid][kg][rA][0]);
        short8 aP1 = *reinterpret_cast<const short8*>(&plds[wid][4+kg][rA][0]);
        #pragma unroll
        for (int dt=0; dt<4; ++dt) {
            const int vo = (dt*16 + rA) * 128;
            short8 bV0 = *reinterpret_cast<const short8*>(Vb + vo + ((kg ^ swz) << 4));
            short8 bV1 = *reinterpret_cast<const short8*>(Vb + vo + (((4+kg) ^ swz) << 4));
            O[dt] = MFMA16(aP0, bV0, O[dt]);
            O[dt] = MFMA16(aP1, bV1, O[dt]);
        }
        __syncthreads();
    }

    float lq[4];
    #pragma unroll
    for (int j=0;j<4;++j) lq[j] = 1.0f / __shfl(l, (kg<<2)+j);
    const int b = bh >> 4, h = bh & 15;
    #pragma unroll
    for (int dt=0; dt<4; ++dt){
        #pragma unroll
        for (int j=0;j<4;++j){
            int t = qrow0 + (kg<<2) + j;
            int col = h*HD + dt*16 + rA;
            merged[((size_t)(b*TSEQ + t))*EMB + col] = __float2bfloat16(O[dt][j]*lq[j]);
        }
    }
}

// ---------------- residual + layer norm ----------------
__global__ __launch_bounds__(256)
void ln_res(const float* __restrict__ a, const float* __restrict__ res,
            const float* __restrict__ gain, const float* __restrict__ bias,
            float* __restrict__ outf, __hip_bfloat16* __restrict__ outb)
{
    const int row = blockIdx.x;
    const int tid = threadIdx.x;
    const int lane = tid & 63, wid = tid >> 6;
    const size_t base = (size_t)row * EMB;
    f32x4 va = *reinterpret_cast<const f32x4*>(a + base + tid*4);
    f32x4 vr = *reinterpret_cast<const f32x4*>(res + base + tid*4);
    f32x4 v = va + vr;
    float s = v[0]+v[1]+v[2]+v[3];
    #pragma unroll
    for (int off=1; off<64; off<<=1) s += __shfl_xor(s, off);
    __shared__ float red1[4], red2[4];
    if (lane==0) red1[wid] = s;
    __syncthreads();
    float mean = (red1[0]+red1[1]+red1[2]+red1[3]) * (1.0f/EMB);
    f32x4 d;
    #pragma unroll
    for (int j=0;j<4;++j) d[j] = v[j] - mean;
    float qs = d[0]*d[0]+d[1]*d[1]+d[2]*d[2]+d[3]*d[3];
    #pragma unroll
    for (int off=1; off<64; off<<=1) qs += __shfl_xor(qs, off);
    if (lane==0) red2[wid] = qs;
    __syncthreads();
    float var = (red2[0]+red2[1]+red2[2]+red2[3]) * (1.0f/EMB);
    float r = 1.0f/(sqrtf(var)+LN_EPS);
    f32x4 g = *reinterpret_cast<const f32x4*>(gain + tid*4);
    f32x4 bb = *reinterpret_cast<const f32x4*>(bias + tid*4);
    f32x4 o;
    #pragma unroll
    for (int j=0;j<4;++j) o[j] = g[j]*(d[j]*r) + bb[j];
    *reinterpret_cast<f32x4*>(outf + base + tid*4) = o;
    if (outb) {
        union { unsigned short us[4]; uint2 u2; } ob;
        #pragma unroll
        for (int j=0;j<4;++j) ob.us[j] = bf16bits(o[j]);
        *reinterpret_cast<uint2*>(reinterpret_cast<unsigned short*>(outb) + base + tid*4) = ob.u2;
    }
}

// ---------------- launch ----------------
extern "C" void kernel_launch(void* const* d_in, const int* in_sizes, int n_in,
                              void* d_out, int out_size, void* d_ws, size_t ws_size,
                              hipStream_t stream) {
    const float* x   = (const float*)d_in[0];
    const float* Wq  = (const float*)d_in[1];
    const float* Wk  = (const float*)d_in[2];
    const float* Wv  = (const float*)d_in[3];
    const float* Wo  = (const float*)d_in[4];
    const float* W1  = (const float*)d_in[5];
    const float* b1  = (const float*)d_in[6];
    const float* W2  = (const float*)d_in[7];
    const float* b2  = (const float*)d_in[8];
    const float* gain1 = (const float*)d_in[9];
    const float* bias1 = (const float*)d_in[10];
    const float* gain2 = (const float*)d_in[11];
    const float* bias2 = (const float*)d_in[12];

    char* ws = (char*)d_ws;
    __hip_bfloat16* Wqkv_t = (__hip_bfloat16*)(ws + 0);          // 3072x1024
    __hip_bfloat16* Wo_t   = (__hip_bfloat16*)(ws + 6291456);    // 1024x1024
    __hip_bfloat16* W1_t   = (__hip_bfloat16*)(ws + 8388608);    // 4096x1024
    __hip_bfloat16* W2_t   = (__hip_bfloat16*)(ws + 16777216);   // 1024x4096
    __hip_bfloat16* xb     = (__hip_bfloat16*)(ws + 25165824);   // 8192x1024
    __hip_bfloat16* qb     = (__hip_bfloat16*)(ws + 41943040);   // 64x2048x64
    __hip_bfloat16* kb     = (__hip_bfloat16*)(ws + 58720256);
    __hip_bfloat16* vtb    = (__hip_bfloat16*)(ws + 75497472);   // 64x64x2048
    __hip_bfloat16* h1     = (__hip_bfloat16*)(ws + 25165824);   // reuse xb..vt, 8192x4096
    __hip_bfloat16* mergedb= (__hip_bfloat16*)(ws + 92274688);   // 8192x1024
    float*          attended=(float*)(ws + 109051904);           // 8192x1024 f32
    float*          ff     = (float*)(ws + 92274688);            // reuse merged+attended
    float*          x1f    = (float*)(ws + 142606336);           // 8192x1024 f32
    __hip_bfloat16* x1b    = (__hip_bfloat16*)(ws + 176160768);  // 8192x1024
    float*          outf   = (float*)d_out;

    dim3 tb(32,8);
    // weight transposes (fp32 -> bf16, N x K)
    transpose_cvt<<<dim3(32,32),  tb, 0, stream>>>(Wq, Wqkv_t,                 1024, 1024);
    transpose_cvt<<<dim3(32,32),  tb, 0, stream>>>(Wk, Wqkv_t + 1024*1024,     1024, 1024);
    transpose_cvt<<<dim3(32,32),  tb, 0, stream>>>(Wv, Wqkv_t + 2*1024*1024,   1024, 1024);
    transpose_cvt<<<dim3(32,32),  tb, 0, stream>>>(Wo, Wo_t,                   1024, 1024);
    transpose_cvt<<<dim3(128,32), tb, 0, stream>>>(W1, W1_t,                   1024, 4096);
    transpose_cvt<<<dim3(32,128), tb, 0, stream>>>(W2, W2_t,                   4096, 1024);
    // x -> bf16
    cvt_bf16<<<(MROWS*EMB/4 + 255)/256, 256, 0, stream>>>(x, xb, MROWS*EMB/4);

    // QKV projection (fused)
    gemm_bt<0><<<dim3(MROWS/128, 3072/128), 256, 0, stream>>>(
        xb, Wqkv_t, MROWS, 3072, EMB, nullptr, nullptr, nullptr, qb, kb, vtb);
    // attention
    attn_fwd<<<dim3(2048), 256, 0, stream>>>(qb, kb, vtb, mergedb);
    // output projection
    gemm_bt<1><<<dim3(MROWS/128, EMB/128), 256, 0, stream>>>(
        mergedb, Wo_t, MROWS, EMB, EMB, attended, nullptr, nullptr, nullptr, nullptr, nullptr);
    // residual + LN1
    ln_res<<<MROWS, 256, 0, stream>>>(attended, x, gain1, bias1, x1f, x1b);
    // FF1: relu(x1 @ W1 + b1) -> bf16
    gemm_bt<2><<<dim3(MROWS/128, DIM_FF/128), 256, 0, stream>>>(
        x1b, W1_t, MROWS, DIM_FF, EMB, nullptr, h1, b1, nullptr, nullptr, nullptr);
    // FF2: h1 @ W2 + b2 -> f32
    gemm_bt<3><<<dim3(MROWS/128, EMB/128), 256, 0, stream>>>(
        h1, W2_t, MROWS, EMB, DIM_FF, ff, nullptr, b2, nullptr, nullptr, nullptr);
    // residual + LN2 -> out
    ln_res<<<MROWS, 256, 0, stream>>>(ff, x1f, gain2, bias2, outf, nullptr);
}